// Round 9
// baseline (716.440 us; speedup 1.0000x reference)
//
#include <hip/hip_runtime.h>

typedef __attribute__((ext_vector_type(8))) short short8;
typedef __attribute__((ext_vector_type(4))) float floatx4;

constexpr int Bb = 2, Ss = 2048, Dd = 1024, Hh = 16, Pp = 128, DHh = 64;
constexpr int NS = Ss + Pp; // 2176

#define DEVI __device__ __forceinline__

#define SYNC_LDS()                                          \
  do {                                                      \
    asm volatile("s_waitcnt lgkmcnt(0)" ::: "memory");      \
    __builtin_amdgcn_s_barrier();                           \
  } while (0)
#define SYNC_VM()                                           \
  do {                                                      \
    asm volatile("s_waitcnt vmcnt(0)" ::: "memory");        \
    __builtin_amdgcn_s_barrier();                           \
  } while (0)
#define SYNC_ALL()                                          \
  do {                                                      \
    asm volatile("s_waitcnt vmcnt(0) lgkmcnt(0)" ::: "memory"); \
    __builtin_amdgcn_s_barrier();                           \
  } while (0)

DEVI unsigned short f2bf(float f) {
  unsigned u = __float_as_uint(f);
  u += 0x7fffu + ((u >> 16) & 1u);
  return (unsigned short)(u >> 16);
}
DEVI float bf2f(unsigned short h) { return __uint_as_float(((unsigned)h) << 16); }

DEVI void gl_lds16(const unsigned short* g, unsigned short* l) {
  __builtin_amdgcn_global_load_lds((const __attribute__((address_space(1))) unsigned int*)g,
                                   (__attribute__((address_space(3))) unsigned int*)l, 16, 0, 0);
}

// ---------------- weight transpose + f32->bf16 ----------------
__global__ __launch_bounds__(256) void wt_cvt_kernel(const float* __restrict__ W,
                                                     unsigned short* __restrict__ Wt,
                                                     int K, int N) {
  __shared__ float t[32][33];
  int n0 = blockIdx.x * 32, k0 = blockIdx.y * 32;
  int tx = threadIdx.x & 31, ty = threadIdx.x >> 5;
#pragma unroll
  for (int j = 0; j < 4; j++)
    t[ty + 8 * j][tx] = W[(long)(k0 + ty + 8 * j) * N + n0 + tx];
  __syncthreads();
#pragma unroll
  for (int j = 0; j < 4; j++)
    Wt[(long)(n0 + ty + 8 * j) * K + k0 + tx] = f2bf(t[tx][ty + 8 * j]);
}

// ---------------- layernorm ----------------
__global__ __launch_bounds__(256) void ln_kernel(const float* __restrict__ x,
                                                 const float* __restrict__ g,
                                                 const float* __restrict__ bia,
                                                 unsigned short* __restrict__ out) {
  int row = blockIdx.x;
  int t = threadIdx.x;
  const float4* xr = (const float4*)(x + (long)row * Dd);
  float4 v = xr[t];
  float s1 = v.x + v.y + v.z + v.w;
  float s2 = v.x * v.x + v.y * v.y + v.z * v.z + v.w * v.w;
#pragma unroll
  for (int o = 1; o < 64; o <<= 1) {
    s1 += __shfl_xor(s1, o);
    s2 += __shfl_xor(s2, o);
  }
  __shared__ float r1[4], r2[4];
  int wid = t >> 6;
  if ((t & 63) == 0) { r1[wid] = s1; r2[wid] = s2; }
  __syncthreads();
  s1 = r1[0] + r1[1] + r1[2] + r1[3];
  s2 = r2[0] + r2[1] + r2[2] + r2[3];
  float mean = s1 * (1.0f / Dd);
  float var = s2 * (1.0f / Dd) - mean * mean;
  float rstd = rsqrtf(var + 1e-3f);
  float4 gg = ((const float4*)g)[t];
  float4 bb = ((const float4*)bia)[t];
  ushort4 o;
  o.x = f2bf((v.x - mean) * rstd * gg.x + bb.x);
  o.y = f2bf((v.y - mean) * rstd * gg.y + bb.y);
  o.z = f2bf((v.z - mean) * rstd * gg.z + bb.z);
  o.w = f2bf((v.w - mean) * rstd * gg.w + bb.w);
  *((ushort4*)(out + (long)row * Dd + t * 4)) = o;
}

// ---------------- split heads / concat past / present ----------------
__global__ __launch_bounds__(256) void split_kernel(const unsigned short* __restrict__ c,
                                                    const float* __restrict__ past,
                                                    unsigned short* __restrict__ q,
                                                    unsigned short* __restrict__ kc_,
                                                    unsigned short* __restrict__ vc_,
                                                    float* __restrict__ present) {
  long idx = (long)blockIdx.x * 256 + threadIdx.x;
  int dh = idx & 63;
  int s = (int)((idx >> 6) & 2047);
  int h = (int)((idx >> 17) & 15);
  int b = (int)(idx >> 21);
  long crow = ((long)(b * Ss + s)) * (3 * Dd);
  int hd = h * DHh + dh;
  unsigned short qv = c[crow + hd];
  unsigned short kv = c[crow + Dd + hd];
  unsigned short vv = c[crow + 2 * Dd + hd];
  long bh = (long)b * Hh + h;
  q[(bh * Ss + s) * DHh + dh] = qv;
  kc_[(bh * NS + Pp + s) * DHh + dh] = kv;
  vc_[(bh * NS + Pp + s) * DHh + dh] = vv;
  present[((((long)b * 2 + 0) * Hh + h) * Ss + s) * DHh + dh] = bf2f(kv);
  present[((((long)b * 2 + 1) * Hh + h) * Ss + s) * DHh + dh] = bf2f(vv);
  if (s < Pp) {
    int p = s;
    float pk = past[((((long)b * 2 + 0) * Hh + h) * Pp + p) * DHh + dh];
    float pv = past[((((long)b * 2 + 1) * Hh + h) * Pp + p) * DHh + dh];
    kc_[(bh * NS + p) * DHh + dh] = f2bf(pk);
    vc_[(bh * NS + p) * DHh + dh] = f2bf(pv);
  }
}

// ---------------- V transpose: (z, NS, 64) -> (z, 64, NS) ----------------
__global__ __launch_bounds__(256) void vtr_kernel(const unsigned short* __restrict__ vcat,
                                                  unsigned short* __restrict__ vT) {
  __shared__ unsigned short Tl[64 * 72];
  int z = blockIdx.y;
  int s0 = blockIdx.x * 64;
  int t = threadIdx.x;
#pragma unroll
  for (int it = 0; it < 2; it++) {
    int idx = t + it * 256, row = idx >> 3, c8 = (idx & 7) * 8;
    *(short8*)&Tl[row * 72 + c8] = *(const short8*)(vcat + ((long)z * NS + s0 + row) * 64 + c8);
  }
  __syncthreads();
#pragma unroll
  for (int it = 0; it < 2; it++) {
    int idx = t + it * 256, row = idx >> 3, c8 = (idx & 7) * 8;
    short8 g;
#pragma unroll
    for (int e = 0; e < 8; e++) g[e] = (short)Tl[(c8 + e) * 72 + row];
    *(short8*)(vT + ((long)z * 64 + row) * NS + s0 + c8) = g;
  }
}

// ---- fused attention, SINGLE PASS: unnormalized p -> w, deferred 1/l rescale ----
// grid 512, 256 threads (4 waves x 32 rows)
__global__ __launch_bounds__(256) void attn_kernel(const unsigned short* __restrict__ qg,
                                                   const unsigned short* __restrict__ kcat,
                                                   const unsigned short* __restrict__ vTg,
                                                   float* __restrict__ wg,
                                                   unsigned short* __restrict__ am) {
  __shared__ unsigned short KV[128 * 72];  // K tile 128x64(+8) / V^T tile 64x128(+8)
  __shared__ unsigned short Pl[128 * 136]; // unnormalized P, bf16
  __shared__ float linv_l[128];
  int wgs = (blockIdx.x & 7) * 64 + (blockIdx.x >> 3);
  int z = wgs >> 4;
  int bx = 15 - (wgs & 15);
  int q0 = bx * 128;
  int t = threadIdx.x, lane = t & 63, wid = t >> 6;
  int lr = lane & 15, kgp = lane >> 4;
  const unsigned short* qz = qg + (long)z * Ss * 64;
  const unsigned short* kz = kcat + (long)z * NS * 64;
  const unsigned short* vz = vTg + (long)z * 64 * NS;
  float* wz = wg + (long)z * Ss * NS;

  short8 qa[2][2];
#pragma unroll
  for (int i = 0; i < 2; i++)
#pragma unroll
    for (int kk = 0; kk < 2; kk++)
      qa[i][kk] =
          *(const short8*)(qz + (long)(q0 + wid * 32 + i * 16 + lr) * 64 + kk * 32 + kgp * 8);

  const int nt = bx + 2;
  float l_part[2][4] = {};   // per-lane partial sums (reduced ONCE after the loop)
  floatx4 oacc[2][4] = {};   // unnormalized PV accumulator

  for (int kt = 0; kt < nt; kt++) {
    // stage K
#pragma unroll
    for (int it = 0; it < 4; it++) {
      int idx = t + it * 256, row = idx >> 3, c8 = (idx & 7) * 8;
      *(short8*)&KV[row * 72 + c8] = *(const short8*)(kz + (long)(kt * 128 + row) * 64 + c8);
    }
    SYNC_LDS();
    floatx4 acc[2][8] = {};
    __builtin_amdgcn_s_setprio(1);
#pragma unroll
    for (int j = 0; j < 8; j++) {
      short8 b0 = *(const short8*)&KV[(j * 16 + lr) * 72 + kgp * 8];
      short8 b1 = *(const short8*)&KV[(j * 16 + lr) * 72 + 32 + kgp * 8];
#pragma unroll
      for (int i = 0; i < 2; i++) {
        acc[i][j] = __builtin_amdgcn_mfma_f32_16x16x32_bf16(qa[i][0], b0, acc[i][j], 0, 0, 0);
        acc[i][j] = __builtin_amdgcn_mfma_f32_16x16x32_bf16(qa[i][1], b1, acc[i][j], 0, 0, 0);
      }
    }
    __builtin_amdgcn_s_setprio(0);
    // p_un = exp(s/8 - 8): store f32 to w (unnormalized), bf16 to Pl, accumulate l
#pragma unroll
    for (int i = 0; i < 2; i++) {
#pragma unroll
      for (int r = 0; r < 4; r++) {
        int row = q0 + wid * 32 + i * 16 + kgp * 4 + r;
        float su = 0.f;
#pragma unroll
        for (int j = 0; j < 8; j++) {
          int col = kt * 128 + j * 16 + lr;
          float p = (col > row + Pp) ? 0.f : __expf(acc[i][j][r] * 0.125f - 8.0f);
          wz[(long)row * NS + col] = p;
          Pl[(wid * 32 + i * 16 + kgp * 4 + r) * 136 + j * 16 + lr] = f2bf(p);
          su += p;
        }
        l_part[i][r] += su; // no per-tile shuffles
      }
    }
    SYNC_LDS(); // K readers done + Pl visible
    // stage V^T
#pragma unroll
    for (int it = 0; it < 4; it++) {
      int idx = t + it * 256, row = idx >> 4, c8 = (idx & 15) * 8;
      *(short8*)&KV[row * 136 + c8] = *(const short8*)(vz + (long)row * NS + kt * 128 + c8);
    }
    SYNC_LDS(); // V^T staged
    __builtin_amdgcn_s_setprio(1);
#pragma unroll
    for (int kk = 0; kk < 4; kk++) {
      short8 pa[2];
#pragma unroll
      for (int i = 0; i < 2; i++)
        pa[i] = *(const short8*)&Pl[(wid * 32 + i * 16 + lr) * 136 + kk * 32 + kgp * 8];
#pragma unroll
      for (int jd = 0; jd < 4; jd++) {
        short8 bv = *(const short8*)&KV[(jd * 16 + lr) * 136 + kk * 32 + kgp * 8];
#pragma unroll
        for (int i = 0; i < 2; i++)
          oacc[i][jd] = __builtin_amdgcn_mfma_f32_16x16x32_bf16(pa[i], bv, oacc[i][jd], 0, 0, 0);
      }
    }
    __builtin_amdgcn_s_setprio(0);
    SYNC_LDS(); // PV readers done before next K staging
  }

  // row sums: one 4-step shuffle reduce across the 16 lr-lanes, then 1/l
  float linv[2][4];
#pragma unroll
  for (int i = 0; i < 2; i++) {
#pragma unroll
    for (int r = 0; r < 4; r++) {
      float su = l_part[i][r];
      su += __shfl_xor(su, 1);
      su += __shfl_xor(su, 2);
      su += __shfl_xor(su, 4);
      su += __shfl_xor(su, 8);
      linv[i][r] = 1.0f / su;
      if (lr == 0) linv_l[wid * 32 + i * 16 + kgp * 4 + r] = linv[i][r];
    }
  }
  // drain all w stores (all waves) + make linv_l visible before rescale reads
  SYNC_ALL();

  // rescale this block's w slab in place (slab is hot in L2)
  {
    int prow = t >> 5, pcol = (t & 31) * 4;
    int cend = nt * 128;
#pragma unroll
    for (int it = 0; it < 16; it++) {
      int row = it * 8 + prow;
      float s = linv_l[row];
      float* wr = &wz[(long)(q0 + row) * NS];
      for (int c = pcol; c < cend; c += 128) {
        float4 v = *(float4*)(wr + c);
        v.x *= s; v.y *= s; v.z *= s; v.w *= s;
        *(float4*)(wr + c) = v;
      }
    }
  }

  // zero-fill fully-masked column range [nt*128, NS)
  int zc0 = nt * 128;
  if (zc0 < NS) {
    for (int rr = 0; rr < 32; rr++) {
      int row = q0 + wid * 32 + rr;
      for (int c = zc0 + (lane << 2); c < NS; c += 256) {
        float4 z4 = {0.f, 0.f, 0.f, 0.f};
        *(float4*)&wz[(long)row * NS + c] = z4;
      }
    }
  }

  // am = oacc_un * (1/l)
#pragma unroll
  for (int i = 0; i < 2; i++)
#pragma unroll
    for (int jd = 0; jd < 4; jd++)
#pragma unroll
      for (int r = 0; r < 4; r++) {
        long row = (long)(z >> 4) * Ss + q0 + wid * 32 + i * 16 + kgp * 4 + r;
        int col = (z & 15) * 64 + jd * 16 + lr;
        am[row * Dd + col] = f2bf(oacc[i][jd][r] * linv[i][r]);
      }
}

// ------- bf16 MFMA GEMM: m97 staging + dbuf prefetch pipeline -------
enum { EPI_BF16_BIAS = 0, EPI_RES = 3, EPI_GELU = 4 };

template <int EPI, int NB>
__global__ __launch_bounds__(256) void gemm_k(const unsigned short* __restrict__ A16,
                                              const unsigned short* __restrict__ Bt,
                                              const float* __restrict__ bias,
                                              const float* __restrict__ res,
                                              void* __restrict__ outv,
                                              int M, int N, int K, int nwg) {
  constexpr int BM = 128, BN = 128;
  __shared__ unsigned short Alds[2][BM * 32];
  __shared__ unsigned short Blds[2][BN * 32];
  int cpx = nwg >> 3;
  int wgid = (blockIdx.x & 7) * cpx + (blockIdx.x >> 3);
  int mb = wgid / NB, nb = wgid % NB;
  int m0 = mb * BM, n0 = nb * BN;
  int t = threadIdx.x;
  int lane = t & 63, wid = t >> 6;
  int wm = wid >> 1, wn = wid & 1;
  floatx4 acc[4][4] = {};
  int lr = lane & 15, kg = lane >> 4;

  const unsigned short* Ab = A16 + (long)(m0 + wid * 32 + (lane >> 2)) * K + (lane & 3) * 8;
  const unsigned short* Bp = Bt + (long)(n0 + wid * 32 + (lane >> 2)) * K + (lane & 3) * 8;
  long rstride = (long)16 * K;
  int lds_w0 = (wid * 32) * 32, lds_w1 = (wid * 32 + 16) * 32;

#define STAGE(bb, k0)                                 \
  do {                                                \
    gl_lds16(Ab + (k0), &Alds[bb][lds_w0]);           \
    gl_lds16(Ab + rstride + (k0), &Alds[bb][lds_w1]); \
    gl_lds16(Bp + (k0), &Blds[bb][lds_w0]);           \
    gl_lds16(Bp + rstride + (k0), &Blds[bb][lds_w1]); \
  } while (0)

  STAGE(0, 0);
  SYNC_VM();
  int cur = 0;
  int nt = K >> 5;
  for (int tt = 0; tt < nt; tt++) {
    if (tt + 1 < nt) STAGE(cur ^ 1, (tt + 1) * 32);
    short8 a[4], b[4];
#pragma unroll
    for (int i = 0; i < 4; i++)
      a[i] = *(const short8*)&Alds[cur][(wm * 64 + i * 16 + lr) * 32 + kg * 8];
#pragma unroll
    for (int j = 0; j < 4; j++)
      b[j] = *(const short8*)&Blds[cur][(wn * 64 + j * 16 + lr) * 32 + kg * 8];
    __builtin_amdgcn_s_setprio(1);
#pragma unroll
    for (int i = 0; i < 4; i++)
#pragma unroll
      for (int j = 0; j < 4; j++)
        acc[i][j] = __builtin_amdgcn_mfma_f32_16x16x32_bf16(a[i], b[j], acc[i][j], 0, 0, 0);
    __builtin_amdgcn_s_setprio(0);
    SYNC_VM();
    cur ^= 1;
  }
#undef STAGE

#pragma unroll
  for (int i = 0; i < 4; i++) {
#pragma unroll
    for (int j = 0; j < 4; j++) {
#pragma unroll
      for (int r = 0; r < 4; r++) {
        int mm = m0 + wm * 64 + i * 16 + kg * 4 + r;
        int nn = n0 + wn * 64 + j * 16 + lr;
        float v = acc[i][j][r];
        if constexpr (EPI == EPI_BF16_BIAS) {
          ((unsigned short*)outv)[(long)mm * N + nn] = f2bf(v + bias[nn]);
        } else if constexpr (EPI == EPI_RES) {
          ((float*)outv)[(long)mm * N + nn] = v + bias[nn] + res[(long)mm * N + nn];
        } else if constexpr (EPI == EPI_GELU) {
          float xv = v + bias[nn];
          float u = xv + 0.044715f * xv * xv * xv;
          float tv = 1.0f - 2.0f / (__expf(1.5957691216057308f * u) + 1.0f);
          ((unsigned short*)outv)[(long)mm * N + nn] = f2bf(0.5f * xv * (1.0f + tv));
        }
      }
    }
  }
}

extern "C" void kernel_launch(void* const* d_in, const int* in_sizes, int n_in,
                              void* d_out, int out_size, void* d_ws, size_t ws_size,
                              hipStream_t stream) {
  (void)in_sizes; (void)n_in; (void)out_size; (void)ws_size;
  const float* x = (const float*)d_in[0];
  const float* past = (const float*)d_in[1];
  const float* qkv_w = (const float*)d_in[2];
  const float* qkv_b = (const float*)d_in[3];
  const float* merge_w = (const float*)d_in[4];
  const float* merge_b = (const float*)d_in[5];
  const float* ln1_w = (const float*)d_in[6];
  const float* ln1_b = (const float*)d_in[7];
  const float* ln2_w = (const float*)d_in[8];
  const float* ln2_b = (const float*)d_in[9];
  const float* g1 = (const float*)d_in[10];
  const float* b1 = (const float*)d_in[11];
  const float* g2 = (const float*)d_in[12];
  const float* b2 = (const float*)d_in[13];

  char* ws = (char*)d_ws;
  unsigned short* qkv_wT = (unsigned short*)(ws + 0);
  unsigned short* merge_wT = (unsigned short*)(ws + 6291456);
  unsigned short* ln1_wT = (unsigned short*)(ws + 8388608);
  unsigned short* ln2_wT = (unsigned short*)(ws + 16777216);
  unsigned short* h = (unsigned short*)(ws + 25165824);
  unsigned short* q = (unsigned short*)(ws + 33554432);
  unsigned short* kcat = (unsigned short*)(ws + 41943040);
  unsigned short* vcat = (unsigned short*)(ws + 50855936);
  unsigned short* c = (unsigned short*)(ws + 59768832);
  unsigned short* am = (unsigned short*)(ws + 59768832);  // reuse c after split
  unsigned short* vT = (unsigned short*)(ws + 68157440);  // in dead c tail during attn
  unsigned short* m1 = (unsigned short*)(ws + 25165824);  // reuse h..vcat after attn
  float* xa = (float*)(ws + 68157440);                    // vT dead by merge GEMM
  unsigned short* h2 = (unsigned short*)(ws + 84934656);

  float* xm_out = (float*)d_out;
  float* present = ((float*)d_out) + (long)Bb * Ss * Dd;
  float* w_out = present + (long)Bb * 2 * Hh * Ss * DHh;

  wt_cvt_kernel<<<dim3(3072 / 32, 1024 / 32), 256, 0, stream>>>(qkv_w, qkv_wT, 1024, 3072);
  wt_cvt_kernel<<<dim3(1024 / 32, 1024 / 32), 256, 0, stream>>>(merge_w, merge_wT, 1024, 1024);
  wt_cvt_kernel<<<dim3(4096 / 32, 1024 / 32), 256, 0, stream>>>(ln1_w, ln1_wT, 1024, 4096);
  wt_cvt_kernel<<<dim3(1024 / 32, 4096 / 32), 256, 0, stream>>>(ln2_w, ln2_wT, 4096, 1024);

  ln_kernel<<<Bb * Ss, 256, 0, stream>>>(x, g1, b1, h);

  gemm_k<EPI_BF16_BIAS, 24><<<32 * 24, 256, 0, stream>>>(
      h, qkv_wT, qkv_b, nullptr, c, 4096, 3072, 1024, 32 * 24);

  split_kernel<<<(Bb * Hh * Ss * DHh) / 256, 256, 0, stream>>>(c, past, q, kcat, vcat, present);

  vtr_kernel<<<dim3(NS / 64, Bb * Hh), 256, 0, stream>>>(vcat, vT);

  attn_kernel<<<512, 256, 0, stream>>>(q, kcat, vT, w_out, am);

  gemm_k<EPI_RES, 8><<<32 * 8, 256, 0, stream>>>(
      am, merge_wT, merge_b, x, xa, 4096, 1024, 1024, 32 * 8);

  ln_kernel<<<Bb * Ss, 256, 0, stream>>>(xa, g2, b2, h2);

  gemm_k<EPI_GELU, 32><<<32 * 32, 256, 0, stream>>>(
      h2, ln1_wT, ln1_b, nullptr, m1, 4096, 4096, 1024, 32 * 32);

  gemm_k<EPI_RES, 8><<<32 * 8, 256, 0, stream>>>(
      m1, ln2_wT, ln2_b, x, xm_out, 4096, 1024, 4096, 32 * 8);
}

// Round 10
// 453.816 us; speedup vs baseline: 1.5787x; 1.5787x over previous
//
#include <hip/hip_runtime.h>

typedef __attribute__((ext_vector_type(8))) short short8;
typedef __attribute__((ext_vector_type(4))) float floatx4;

constexpr int Bb = 2, Ss = 2048, Dd = 1024, Hh = 16, Pp = 128, DHh = 64;
constexpr int NS = Ss + Pp; // 2176

#define DEVI __device__ __forceinline__

#define SYNC_LDS()                                          \
  do {                                                      \
    asm volatile("s_waitcnt lgkmcnt(0)" ::: "memory");      \
    __builtin_amdgcn_s_barrier();                           \
  } while (0)
#define SYNC_VM()                                           \
  do {                                                      \
    asm volatile("s_waitcnt vmcnt(0)" ::: "memory");        \
    __builtin_amdgcn_s_barrier();                           \
  } while (0)

DEVI unsigned short f2bf(float f) {
  unsigned u = __float_as_uint(f);
  u += 0x7fffu + ((u >> 16) & 1u);
  return (unsigned short)(u >> 16);
}
DEVI float bf2f(unsigned short h) { return __uint_as_float(((unsigned)h) << 16); }

DEVI void gl_lds16(const unsigned short* g, unsigned short* l) {
  __builtin_amdgcn_global_load_lds((const __attribute__((address_space(1))) unsigned int*)g,
                                   (__attribute__((address_space(3))) unsigned int*)l, 16, 0, 0);
}

// ---------------- weight transpose + f32->bf16 ----------------
__global__ __launch_bounds__(256) void wt_cvt_kernel(const float* __restrict__ W,
                                                     unsigned short* __restrict__ Wt,
                                                     int K, int N) {
  __shared__ float t[32][33];
  int n0 = blockIdx.x * 32, k0 = blockIdx.y * 32;
  int tx = threadIdx.x & 31, ty = threadIdx.x >> 5;
#pragma unroll
  for (int j = 0; j < 4; j++)
    t[ty + 8 * j][tx] = W[(long)(k0 + ty + 8 * j) * N + n0 + tx];
  __syncthreads();
#pragma unroll
  for (int j = 0; j < 4; j++)
    Wt[(long)(n0 + ty + 8 * j) * K + k0 + tx] = f2bf(t[tx][ty + 8 * j]);
}

// ---------------- layernorm ----------------
__global__ __launch_bounds__(256) void ln_kernel(const float* __restrict__ x,
                                                 const float* __restrict__ g,
                                                 const float* __restrict__ bia,
                                                 unsigned short* __restrict__ out) {
  int row = blockIdx.x;
  int t = threadIdx.x;
  const float4* xr = (const float4*)(x + (long)row * Dd);
  float4 v = xr[t];
  float s1 = v.x + v.y + v.z + v.w;
  float s2 = v.x * v.x + v.y * v.y + v.z * v.z + v.w * v.w;
#pragma unroll
  for (int o = 1; o < 64; o <<= 1) {
    s1 += __shfl_xor(s1, o);
    s2 += __shfl_xor(s2, o);
  }
  __shared__ float r1[4], r2[4];
  int wid = t >> 6;
  if ((t & 63) == 0) { r1[wid] = s1; r2[wid] = s2; }
  __syncthreads();
  s1 = r1[0] + r1[1] + r1[2] + r1[3];
  s2 = r2[0] + r2[1] + r2[2] + r2[3];
  float mean = s1 * (1.0f / Dd);
  float var = s2 * (1.0f / Dd) - mean * mean;
  float rstd = rsqrtf(var + 1e-3f);
  float4 gg = ((const float4*)g)[t];
  float4 bb = ((const float4*)bia)[t];
  ushort4 o;
  o.x = f2bf((v.x - mean) * rstd * gg.x + bb.x);
  o.y = f2bf((v.y - mean) * rstd * gg.y + bb.y);
  o.z = f2bf((v.z - mean) * rstd * gg.z + bb.z);
  o.w = f2bf((v.w - mean) * rstd * gg.w + bb.w);
  *((ushort4*)(out + (long)row * Dd + t * 4)) = o;
}

// ---------------- split heads / concat past / present ----------------
__global__ __launch_bounds__(256) void split_kernel(const unsigned short* __restrict__ c,
                                                    const float* __restrict__ past,
                                                    unsigned short* __restrict__ q,
                                                    unsigned short* __restrict__ kc_,
                                                    unsigned short* __restrict__ vc_,
                                                    float* __restrict__ present) {
  long idx = (long)blockIdx.x * 256 + threadIdx.x;
  int dh = idx & 63;
  int s = (int)((idx >> 6) & 2047);
  int h = (int)((idx >> 17) & 15);
  int b = (int)(idx >> 21);
  long crow = ((long)(b * Ss + s)) * (3 * Dd);
  int hd = h * DHh + dh;
  unsigned short qv = c[crow + hd];
  unsigned short kv = c[crow + Dd + hd];
  unsigned short vv = c[crow + 2 * Dd + hd];
  long bh = (long)b * Hh + h;
  q[(bh * Ss + s) * DHh + dh] = qv;
  kc_[(bh * NS + Pp + s) * DHh + dh] = kv;
  vc_[(bh * NS + Pp + s) * DHh + dh] = vv;
  present[((((long)b * 2 + 0) * Hh + h) * Ss + s) * DHh + dh] = bf2f(kv);
  present[((((long)b * 2 + 1) * Hh + h) * Ss + s) * DHh + dh] = bf2f(vv);
  if (s < Pp) {
    int p = s;
    float pk = past[((((long)b * 2 + 0) * Hh + h) * Pp + p) * DHh + dh];
    float pv = past[((((long)b * 2 + 1) * Hh + h) * Pp + p) * DHh + dh];
    kc_[(bh * NS + p) * DHh + dh] = f2bf(pk);
    vc_[(bh * NS + p) * DHh + dh] = f2bf(pv);
  }
}

// ---------------- V transpose: (z, NS, 64) -> (z, 64, NS) ----------------
__global__ __launch_bounds__(256) void vtr_kernel(const unsigned short* __restrict__ vcat,
                                                  unsigned short* __restrict__ vT) {
  __shared__ unsigned short Tl[64 * 72];
  int z = blockIdx.y;
  int s0 = blockIdx.x * 64;
  int t = threadIdx.x;
#pragma unroll
  for (int it = 0; it < 2; it++) {
    int idx = t + it * 256, row = idx >> 3, c8 = (idx & 7) * 8;
    *(short8*)&Tl[row * 72 + c8] = *(const short8*)(vcat + ((long)z * NS + s0 + row) * 64 + c8);
  }
  __syncthreads();
#pragma unroll
  for (int it = 0; it < 2; it++) {
    int idx = t + it * 256, row = idx >> 3, c8 = (idx & 7) * 8;
    short8 g;
#pragma unroll
    for (int e = 0; e < 8; e++) g[e] = (short)Tl[(c8 + e) * 72 + row];
    *(short8*)(vT + ((long)z * 64 + row) * NS + s0 + c8) = g;
  }
}

// ---- fused attention: two-pass (round-8) + T14 async-stage dbuf in pass 1 ----
// grid 512, 256 threads (4 waves x 32 rows)
__global__ __launch_bounds__(256) void attn_kernel(const unsigned short* __restrict__ qg,
                                                   const unsigned short* __restrict__ kcat,
                                                   const unsigned short* __restrict__ vTg,
                                                   float* __restrict__ wg,
                                                   unsigned short* __restrict__ am) {
  __shared__ unsigned short KV[128 * 72];  // K tile / V^T tile (pass 2)
  __shared__ unsigned short Pl[128 * 136]; // P tile (pass 2); K dbuf (pass 1)
  int wgs = (blockIdx.x & 7) * 64 + (blockIdx.x >> 3);
  int z = wgs >> 4;
  int bx = 15 - (wgs & 15);
  int q0 = bx * 128;
  int t = threadIdx.x, lane = t & 63, wid = t >> 6;
  int lr = lane & 15, kgp = lane >> 4;
  const unsigned short* qz = qg + (long)z * Ss * 64;
  const unsigned short* kz = kcat + (long)z * NS * 64;
  const unsigned short* vz = vTg + (long)z * 64 * NS;
  float* wz = wg + (long)z * Ss * NS;

  short8 qa[2][2];
#pragma unroll
  for (int i = 0; i < 2; i++)
#pragma unroll
    for (int kk = 0; kk < 2; kk++)
      qa[i][kk] =
          *(const short8*)(qz + (long)(q0 + wid * 32 + i * 16 + lr) * 64 + kk * 32 + kgp * 8);

  const int nt = bx + 2;
  float l_run[2][4] = {};

  // ---- pass 1: denominators; K double-buffered (KV / Pl), 1 barrier per tile ----
  {
    unsigned short* kb0 = KV;
    unsigned short* kb1 = Pl; // Pl unused in pass 1
    short8 kreg[4];
    // prologue: load tile 0 -> regs -> buf0
#pragma unroll
    for (int it = 0; it < 4; it++) {
      int idx = t + it * 256, row = idx >> 3, c8 = (idx & 7) * 8;
      kreg[it] = *(const short8*)(kz + (long)row * 64 + c8);
    }
#pragma unroll
    for (int it = 0; it < 4; it++) {
      int idx = t + it * 256, row = idx >> 3, c8 = (idx & 7) * 8;
      *(short8*)&kb0[row * 72 + c8] = kreg[it];
    }
    for (int kt = 0; kt < nt; kt++) {
      unsigned short* bc = (kt & 1) ? kb1 : kb0;
      unsigned short* bn = (kt & 1) ? kb0 : kb1;
      // issue next tile's global loads early (latency hides under MFMA+exp)
      if (kt + 1 < nt) {
#pragma unroll
        for (int it = 0; it < 4; it++) {
          int idx = t + it * 256, row = idx >> 3, c8 = (idx & 7) * 8;
          kreg[it] = *(const short8*)(kz + (long)((kt + 1) * 128 + row) * 64 + c8);
        }
      }
      SYNC_LDS(); // buf[cur] (written last iter) visible to all waves
      floatx4 acc[2][8] = {};
      __builtin_amdgcn_s_setprio(1);
#pragma unroll
      for (int j = 0; j < 8; j++) {
        short8 b0 = *(const short8*)&bc[(j * 16 + lr) * 72 + kgp * 8];
        short8 b1 = *(const short8*)&bc[(j * 16 + lr) * 72 + 32 + kgp * 8];
#pragma unroll
        for (int i = 0; i < 2; i++) {
          acc[i][j] = __builtin_amdgcn_mfma_f32_16x16x32_bf16(qa[i][0], b0, acc[i][j], 0, 0, 0);
          acc[i][j] = __builtin_amdgcn_mfma_f32_16x16x32_bf16(qa[i][1], b1, acc[i][j], 0, 0, 0);
        }
      }
      __builtin_amdgcn_s_setprio(0);
#pragma unroll
      for (int i = 0; i < 2; i++) {
#pragma unroll
        for (int r = 0; r < 4; r++) {
          int row = q0 + wid * 32 + i * 16 + kgp * 4 + r;
          float su = 0.f;
#pragma unroll
          for (int j = 0; j < 8; j++) {
            int col = kt * 128 + j * 16 + lr;
            su += (col > row + Pp) ? 0.f : __expf(acc[i][j][r] * 0.125f - 8.0f);
          }
          su += __shfl_xor(su, 1);
          su += __shfl_xor(su, 2);
          su += __shfl_xor(su, 4);
          su += __shfl_xor(su, 8);
          l_run[i][r] += su;
        }
      }
      // write prefetched tile into the other buffer (drained by next SYNC_LDS)
      if (kt + 1 < nt) {
#pragma unroll
        for (int it = 0; it < 4; it++) {
          int idx = t + it * 256, row = idx >> 3, c8 = (idx & 7) * 8;
          *(short8*)&bn[row * 72 + c8] = kreg[it];
        }
      }
    }
  }
  SYNC_LDS(); // all waves done with pass-1 buffers before pass 2 overwrites

  float cc[2][4];
#pragma unroll
  for (int i = 0; i < 2; i++)
#pragma unroll
    for (int r = 0; r < 4; r++) cc[i][r] = 8.0f + __logf(l_run[i][r]);

  // ---- pass 2: w + PV (round-8 structure) ----
  floatx4 oacc[2][4] = {};
  for (int kt = 0; kt < nt; kt++) {
#pragma unroll
    for (int it = 0; it < 4; it++) {
      int idx = t + it * 256, row = idx >> 3, c8 = (idx & 7) * 8;
      *(short8*)&KV[row * 72 + c8] = *(const short8*)(kz + (long)(kt * 128 + row) * 64 + c8);
    }
    SYNC_LDS();
    floatx4 acc[2][8] = {};
    __builtin_amdgcn_s_setprio(1);
#pragma unroll
    for (int j = 0; j < 8; j++) {
      short8 b0 = *(const short8*)&KV[(j * 16 + lr) * 72 + kgp * 8];
      short8 b1 = *(const short8*)&KV[(j * 16 + lr) * 72 + 32 + kgp * 8];
#pragma unroll
      for (int i = 0; i < 2; i++) {
        acc[i][j] = __builtin_amdgcn_mfma_f32_16x16x32_bf16(qa[i][0], b0, acc[i][j], 0, 0, 0);
        acc[i][j] = __builtin_amdgcn_mfma_f32_16x16x32_bf16(qa[i][1], b1, acc[i][j], 0, 0, 0);
      }
    }
    __builtin_amdgcn_s_setprio(0);
#pragma unroll
    for (int i = 0; i < 2; i++) {
#pragma unroll
      for (int r = 0; r < 4; r++) {
        int row = q0 + wid * 32 + i * 16 + kgp * 4 + r;
#pragma unroll
        for (int j = 0; j < 8; j++) {
          int col = kt * 128 + j * 16 + lr;
          float p = (col > row + Pp) ? 0.f : __expf(acc[i][j][r] * 0.125f - cc[i][r]);
          Pl[(wid * 32 + i * 16 + kgp * 4 + r) * 136 + j * 16 + lr] = f2bf(p);
        }
      }
    }
    SYNC_LDS(); // K readers done + Pl visible
    // stage V^T + coalesced w stores from Pl
#pragma unroll
    for (int it = 0; it < 4; it++) {
      int idx = t + it * 256, row = idx >> 4, c8 = (idx & 15) * 8;
      *(short8*)&KV[row * 136 + c8] = *(const short8*)(vz + (long)row * NS + kt * 128 + c8);
    }
    {
      int prow = t >> 5, pcol = (t & 31) * 4;
#pragma unroll
      for (int it = 0; it < 16; it++) {
        int row = it * 8 + prow;
        unsigned short p0 = Pl[row * 136 + pcol];
        unsigned short p1 = Pl[row * 136 + pcol + 1];
        unsigned short p2 = Pl[row * 136 + pcol + 2];
        unsigned short p3 = Pl[row * 136 + pcol + 3];
        float4 f;
        f.x = bf2f(p0);
        f.y = bf2f(p1);
        f.z = bf2f(p2);
        f.w = bf2f(p3);
        *(float4*)&wz[(long)(q0 + row) * NS + kt * 128 + pcol] = f;
      }
    }
    SYNC_LDS(); // V^T staged
    __builtin_amdgcn_s_setprio(1);
#pragma unroll
    for (int kk = 0; kk < 4; kk++) {
      short8 pa[2];
#pragma unroll
      for (int i = 0; i < 2; i++)
        pa[i] = *(const short8*)&Pl[(wid * 32 + i * 16 + lr) * 136 + kk * 32 + kgp * 8];
#pragma unroll
      for (int jd = 0; jd < 4; jd++) {
        short8 bv = *(const short8*)&KV[(jd * 16 + lr) * 136 + kk * 32 + kgp * 8];
#pragma unroll
        for (int i = 0; i < 2; i++)
          oacc[i][jd] = __builtin_amdgcn_mfma_f32_16x16x32_bf16(pa[i], bv, oacc[i][jd], 0, 0, 0);
      }
    }
    __builtin_amdgcn_s_setprio(0);
    SYNC_LDS(); // PV readers done before next K staging
  }

  int zc0 = nt * 128;
  if (zc0 < NS) {
    for (int rr = 0; rr < 32; rr++) {
      int row = q0 + wid * 32 + rr;
      for (int c = zc0 + (lane << 2); c < NS; c += 256) {
        float4 z4 = {0.f, 0.f, 0.f, 0.f};
        *(float4*)&wz[(long)row * NS + c] = z4;
      }
    }
  }

#pragma unroll
  for (int i = 0; i < 2; i++)
#pragma unroll
    for (int jd = 0; jd < 4; jd++)
#pragma unroll
      for (int r = 0; r < 4; r++) {
        long row = (long)(z >> 4) * Ss + q0 + wid * 32 + i * 16 + kgp * 4 + r;
        int col = (z & 15) * 64 + jd * 16 + lr;
        am[row * Dd + col] = f2bf(oacc[i][jd][r]);
      }
}

// ------- bf16 MFMA GEMM: m97 staging + dbuf prefetch pipeline -------
enum { EPI_BF16_BIAS = 0, EPI_RES = 3, EPI_GELU = 4 };

template <int EPI, int NB>
__global__ __launch_bounds__(256) void gemm_k(const unsigned short* __restrict__ A16,
                                              const unsigned short* __restrict__ Bt,
                                              const float* __restrict__ bias,
                                              const float* __restrict__ res,
                                              void* __restrict__ outv,
                                              int M, int N, int K, int nwg) {
  constexpr int BM = 128, BN = 128;
  __shared__ unsigned short Alds[2][BM * 32];
  __shared__ unsigned short Blds[2][BN * 32];
  int cpx = nwg >> 3;
  int wgid = (blockIdx.x & 7) * cpx + (blockIdx.x >> 3);
  int mb = wgid / NB, nb = wgid % NB;
  int m0 = mb * BM, n0 = nb * BN;
  int t = threadIdx.x;
  int lane = t & 63, wid = t >> 6;
  int wm = wid >> 1, wn = wid & 1;
  floatx4 acc[4][4] = {};
  int lr = lane & 15, kg = lane >> 4;

  const unsigned short* Ab = A16 + (long)(m0 + wid * 32 + (lane >> 2)) * K + (lane & 3) * 8;
  const unsigned short* Bp = Bt + (long)(n0 + wid * 32 + (lane >> 2)) * K + (lane & 3) * 8;
  long rstride = (long)16 * K;
  int lds_w0 = (wid * 32) * 32, lds_w1 = (wid * 32 + 16) * 32;

#define STAGE(bb, k0)                                 \
  do {                                                \
    gl_lds16(Ab + (k0), &Alds[bb][lds_w0]);           \
    gl_lds16(Ab + rstride + (k0), &Alds[bb][lds_w1]); \
    gl_lds16(Bp + (k0), &Blds[bb][lds_w0]);           \
    gl_lds16(Bp + rstride + (k0), &Blds[bb][lds_w1]); \
  } while (0)

  STAGE(0, 0);
  SYNC_VM();
  int cur = 0;
  int nt = K >> 5;
  for (int tt = 0; tt < nt; tt++) {
    if (tt + 1 < nt) STAGE(cur ^ 1, (tt + 1) * 32);
    short8 a[4], b[4];
#pragma unroll
    for (int i = 0; i < 4; i++)
      a[i] = *(const short8*)&Alds[cur][(wm * 64 + i * 16 + lr) * 32 + kg * 8];
#pragma unroll
    for (int j = 0; j < 4; j++)
      b[j] = *(const short8*)&Blds[cur][(wn * 64 + j * 16 + lr) * 32 + kg * 8];
    __builtin_amdgcn_s_setprio(1);
#pragma unroll
    for (int i = 0; i < 4; i++)
#pragma unroll
      for (int j = 0; j < 4; j++)
        acc[i][j] = __builtin_amdgcn_mfma_f32_16x16x32_bf16(a[i], b[j], acc[i][j], 0, 0, 0);
    __builtin_amdgcn_s_setprio(0);
    SYNC_VM();
    cur ^= 1;
  }
#undef STAGE

#pragma unroll
  for (int i = 0; i < 4; i++) {
#pragma unroll
    for (int j = 0; j < 4; j++) {
#pragma unroll
      for (int r = 0; r < 4; r++) {
        int mm = m0 + wm * 64 + i * 16 + kg * 4 + r;
        int nn = n0 + wn * 64 + j * 16 + lr;
        float v = acc[i][j][r];
        if constexpr (EPI == EPI_BF16_BIAS) {
          ((unsigned short*)outv)[(long)mm * N + nn] = f2bf(v + bias[nn]);
        } else if constexpr (EPI == EPI_RES) {
          ((float*)outv)[(long)mm * N + nn] = v + bias[nn] + res[(long)mm * N + nn];
        } else if constexpr (EPI == EPI_GELU) {
          float xv = v + bias[nn];
          float u = xv + 0.044715f * xv * xv * xv;
          float tv = 1.0f - 2.0f / (__expf(1.5957691216057308f * u) + 1.0f);
          ((unsigned short*)outv)[(long)mm * N + nn] = f2bf(0.5f * xv * (1.0f + tv));
        }
      }
    }
  }
}

extern "C" void kernel_launch(void* const* d_in, const int* in_sizes, int n_in,
                              void* d_out, int out_size, void* d_ws, size_t ws_size,
                              hipStream_t stream) {
  (void)in_sizes; (void)n_in; (void)out_size; (void)ws_size;
  const float* x = (const float*)d_in[0];
  const float* past = (const float*)d_in[1];
  const float* qkv_w = (const float*)d_in[2];
  const float* qkv_b = (const float*)d_in[3];
  const float* merge_w = (const float*)d_in[4];
  const float* merge_b = (const float*)d_in[5];
  const float* ln1_w = (const float*)d_in[6];
  const float* ln1_b = (const float*)d_in[7];
  const float* ln2_w = (const float*)d_in[8];
  const float* ln2_b = (const float*)d_in[9];
  const float* g1 = (const float*)d_in[10];
  const float* b1 = (const float*)d_in[11];
  const float* g2 = (const float*)d_in[12];
  const float* b2 = (const float*)d_in[13];

  char* ws = (char*)d_ws;
  unsigned short* qkv_wT = (unsigned short*)(ws + 0);
  unsigned short* merge_wT = (unsigned short*)(ws + 6291456);
  unsigned short* ln1_wT = (unsigned short*)(ws + 8388608);
  unsigned short* ln2_wT = (unsigned short*)(ws + 16777216);
  unsigned short* h = (unsigned short*)(ws + 25165824);
  unsigned short* q = (unsigned short*)(ws + 33554432);
  unsigned short* kcat = (unsigned short*)(ws + 41943040);
  unsigned short* vcat = (unsigned short*)(ws + 50855936);
  unsigned short* c = (unsigned short*)(ws + 59768832);
  unsigned short* am = (unsigned short*)(ws + 59768832);  // reuse c after split
  unsigned short* vT = (unsigned short*)(ws + 68157440);  // in dead c tail during attn
  unsigned short* m1 = (unsigned short*)(ws + 25165824);  // reuse h..vcat after attn
  float* xa = (float*)(ws + 68157440);                    // vT dead by merge GEMM
  unsigned short* h2 = (unsigned short*)(ws + 84934656);

  float* xm_out = (float*)d_out;
  float* present = ((float*)d_out) + (long)Bb * Ss * Dd;
  float* w_out = present + (long)Bb * 2 * Hh * Ss * DHh;

  wt_cvt_kernel<<<dim3(3072 / 32, 1024 / 32), 256, 0, stream>>>(qkv_w, qkv_wT, 1024, 3072);
  wt_cvt_kernel<<<dim3(1024 / 32, 1024 / 32), 256, 0, stream>>>(merge_w, merge_wT, 1024, 1024);
  wt_cvt_kernel<<<dim3(4096 / 32, 1024 / 32), 256, 0, stream>>>(ln1_w, ln1_wT, 1024, 4096);
  wt_cvt_kernel<<<dim3(1024 / 32, 4096 / 32), 256, 0, stream>>>(ln2_w, ln2_wT, 4096, 1024);

  ln_kernel<<<Bb * Ss, 256, 0, stream>>>(x, g1, b1, h);

  gemm_k<EPI_BF16_BIAS, 24><<<32 * 24, 256, 0, stream>>>(
      h, qkv_wT, qkv_b, nullptr, c, 4096, 3072, 1024, 32 * 24);

  split_kernel<<<(Bb * Hh * Ss * DHh) / 256, 256, 0, stream>>>(c, past, q, kcat, vcat, present);

  vtr_kernel<<<dim3(NS / 64, Bb * Hh), 256, 0, stream>>>(vcat, vT);

  attn_kernel<<<512, 256, 0, stream>>>(q, kcat, vT, w_out, am);

  gemm_k<EPI_RES, 8><<<32 * 8, 256, 0, stream>>>(
      am, merge_wT, merge_b, x, xa, 4096, 1024, 1024, 32 * 8);

  ln_kernel<<<Bb * Ss, 256, 0, stream>>>(xa, g2, b2, h2);

  gemm_k<EPI_GELU, 32><<<32 * 32, 256, 0, stream>>>(
      h2, ln1_wT, ln1_b, nullptr, m1, 4096, 4096, 1024, 32 * 32);

  gemm_k<EPI_RES, 8><<<32 * 8, 256, 0, stream>>>(
      m1, ln2_wT, ln2_b, x, xm_out, 4096, 1024, 4096, 32 * 8);
}

// Round 11
// 420.874 us; speedup vs baseline: 1.7023x; 1.0783x over previous
//
#include <hip/hip_runtime.h>

typedef __attribute__((ext_vector_type(8))) short short8;
typedef __attribute__((ext_vector_type(4))) float floatx4;

constexpr int Bb = 2, Ss = 2048, Dd = 1024, Hh = 16, Pp = 128, DHh = 64;
constexpr int NS = Ss + Pp; // 2176

#define DEVI __device__ __forceinline__

#define SYNC_LDS()                                          \
  do {                                                      \
    asm volatile("s_waitcnt lgkmcnt(0)" ::: "memory");      \
    __builtin_amdgcn_s_barrier();                           \
  } while (0)
#define SYNC_VM()                                           \
  do {                                                      \
    asm volatile("s_waitcnt vmcnt(0)" ::: "memory");        \
    __builtin_amdgcn_s_barrier();                           \
  } while (0)

DEVI unsigned short f2bf(float f) {
  unsigned u = __float_as_uint(f);
  u += 0x7fffu + ((u >> 16) & 1u);
  return (unsigned short)(u >> 16);
}
DEVI float bf2f(unsigned short h) { return __uint_as_float(((unsigned)h) << 16); }

DEVI void gl_lds16(const unsigned short* g, unsigned short* l) {
  __builtin_amdgcn_global_load_lds((const __attribute__((address_space(1))) unsigned int*)g,
                                   (__attribute__((address_space(3))) unsigned int*)l, 16, 0, 0);
}

// ------- fused weight transpose + f32->bf16 for all 4 weights, one launch -------
__global__ __launch_bounds__(256) void wt_cvt_all_kernel(const float* __restrict__ qkv_w,
                                                         const float* __restrict__ merge_w,
                                                         const float* __restrict__ ln1_w,
                                                         const float* __restrict__ ln2_w,
                                                         unsigned short* __restrict__ qkv_wT,
                                                         unsigned short* __restrict__ merge_wT,
                                                         unsigned short* __restrict__ ln1_wT,
                                                         unsigned short* __restrict__ ln2_wT) {
  __shared__ float tl[32][33];
  int bid = blockIdx.x;
  const float* W;
  unsigned short* Wt;
  int K, N, bx, by;
  if (bid < 3072) {            // qkv: N=3072,K=1024 -> 96 x 32
    W = qkv_w; Wt = qkv_wT; K = 1024; N = 3072; bx = bid % 96; by = bid / 96;
  } else if (bid < 4096) {     // merge: 32 x 32
    int b2 = bid - 3072; W = merge_w; Wt = merge_wT; K = 1024; N = 1024; bx = b2 % 32; by = b2 / 32;
  } else if (bid < 8192) {     // ln1: N=4096,K=1024 -> 128 x 32
    int b3 = bid - 4096; W = ln1_w; Wt = ln1_wT; K = 1024; N = 4096; bx = b3 % 128; by = b3 / 128;
  } else {                     // ln2: N=1024,K=4096 -> 32 x 128
    int b4 = bid - 8192; W = ln2_w; Wt = ln2_wT; K = 4096; N = 1024; bx = b4 % 32; by = b4 / 32;
  }
  int n0 = bx * 32, k0 = by * 32;
  int tx = threadIdx.x & 31, ty = threadIdx.x >> 5;
#pragma unroll
  for (int j = 0; j < 4; j++)
    tl[ty + 8 * j][tx] = W[(long)(k0 + ty + 8 * j) * N + n0 + tx];
  __syncthreads();
#pragma unroll
  for (int j = 0; j < 4; j++)
    Wt[(long)(n0 + ty + 8 * j) * K + k0 + tx] = f2bf(tl[tx][ty + 8 * j]);
}

// ---------------- layernorm ----------------
__global__ __launch_bounds__(256) void ln_kernel(const float* __restrict__ x,
                                                 const float* __restrict__ g,
                                                 const float* __restrict__ bia,
                                                 unsigned short* __restrict__ out) {
  int row = blockIdx.x;
  int t = threadIdx.x;
  const float4* xr = (const float4*)(x + (long)row * Dd);
  float4 v = xr[t];
  float s1 = v.x + v.y + v.z + v.w;
  float s2 = v.x * v.x + v.y * v.y + v.z * v.z + v.w * v.w;
#pragma unroll
  for (int o = 1; o < 64; o <<= 1) {
    s1 += __shfl_xor(s1, o);
    s2 += __shfl_xor(s2, o);
  }
  __shared__ float r1[4], r2[4];
  int wid = t >> 6;
  if ((t & 63) == 0) { r1[wid] = s1; r2[wid] = s2; }
  __syncthreads();
  s1 = r1[0] + r1[1] + r1[2] + r1[3];
  s2 = r2[0] + r2[1] + r2[2] + r2[3];
  float mean = s1 * (1.0f / Dd);
  float var = s2 * (1.0f / Dd) - mean * mean;
  float rstd = rsqrtf(var + 1e-3f);
  float4 gg = ((const float4*)g)[t];
  float4 bb = ((const float4*)bia)[t];
  ushort4 o;
  o.x = f2bf((v.x - mean) * rstd * gg.x + bb.x);
  o.y = f2bf((v.y - mean) * rstd * gg.y + bb.y);
  o.z = f2bf((v.z - mean) * rstd * gg.z + bb.z);
  o.w = f2bf((v.w - mean) * rstd * gg.w + bb.w);
  *((ushort4*)(out + (long)row * Dd + t * 4)) = o;
}

// ---- prep: present emission (from c) + kp16 (past K bf16) + vT past columns ----
// blocks [0,16384): present; [16384,17408): kp16; [17408,18432): vT past
__global__ __launch_bounds__(256) void prep_kernel(const unsigned short* __restrict__ c,
                                                   const float* __restrict__ past,
                                                   float* __restrict__ present,
                                                   unsigned short* __restrict__ kp16,
                                                   unsigned short* __restrict__ vT) {
  long bid = blockIdx.x;
  if (bid < 16384) {
    long i = bid * 256 + threadIdx.x; // (b,h,s,dh)
    int dh = (int)(i & 63);
    int s = (int)((i >> 6) & 2047);
    int h = (int)((i >> 17) & 15);
    int b = (int)(i >> 21);
    long crow = ((long)b * Ss + s) * (3 * Dd) + h * DHh + dh;
    unsigned short kv = c[crow + Dd];
    unsigned short vv = c[crow + 2 * Dd];
    present[((((long)b * 2 + 0) * Hh + h) * Ss + s) * DHh + dh] = bf2f(kv);
    present[((((long)b * 2 + 1) * Hh + h) * Ss + s) * DHh + dh] = bf2f(vv);
  } else if (bid < 17408) {
    long j = (bid - 16384) * 256 + threadIdx.x; // (z,p,dh)
    int dh = (int)(j & 63);
    int p = (int)((j >> 6) & 127);
    int z = (int)(j >> 13);
    int b = z >> 4, h = z & 15;
    float pk = past[((((long)b * 2 + 0) * Hh + h) * Pp + p) * DHh + dh];
    kp16[((long)z * Pp + p) * DHh + dh] = f2bf(pk);
  } else {
    long j = (bid - 17408) * 256 + threadIdx.x; // (z,dh,p)
    int p = (int)(j & 127);
    int dh = (int)((j >> 7) & 63);
    int z = (int)(j >> 13);
    int b = z >> 4, h = z & 15;
    float pv = past[((((long)b * 2 + 1) * Hh + h) * Pp + p) * DHh + dh];
    vT[((long)z * DHh + dh) * NS + p] = f2bf(pv);
  }
}

// ---------------- V transpose from c: fills vT cols [128, NS) ----------------
__global__ __launch_bounds__(256) void vtr_kernel(const unsigned short* __restrict__ c,
                                                  unsigned short* __restrict__ vT) {
  __shared__ unsigned short Tl[64 * 72];
  int z = blockIdx.y;
  int b = z >> 4, h = z & 15;
  int s0 = Pp + blockIdx.x * 64; // 128..2112
  int t = threadIdx.x;
#pragma unroll
  for (int it = 0; it < 2; it++) {
    int idx = t + it * 256, row = idx >> 3, c8 = (idx & 7) * 8;
    *(short8*)&Tl[row * 72 + c8] =
        *(const short8*)(c + ((long)b * Ss + s0 - Pp + row) * (3 * Dd) + 2 * Dd + h * DHh + c8);
  }
  __syncthreads();
#pragma unroll
  for (int it = 0; it < 2; it++) {
    int idx = t + it * 256, row = idx >> 3, c8 = (idx & 7) * 8;
    short8 g;
#pragma unroll
    for (int e = 0; e < 8; e++) g[e] = (short)Tl[(c8 + e) * 72 + row];
    *(short8*)(vT + ((long)z * DHh + row) * NS + s0 + c8) = g;
  }
}

// ---- fused attention (round-8 two-pass); Q/K sourced from c + kp16 ----
// grid 512, 256 threads (4 waves x 32 rows)
__global__ __launch_bounds__(256) void attn_kernel(const unsigned short* __restrict__ c,
                                                   const unsigned short* __restrict__ kp16,
                                                   const unsigned short* __restrict__ vTg,
                                                   float* __restrict__ wg,
                                                   unsigned short* __restrict__ am) {
  __shared__ unsigned short KV[128 * 72];
  __shared__ unsigned short Pl[128 * 136];
  int wgs = (blockIdx.x & 7) * 64 + (blockIdx.x >> 3);
  int z = wgs >> 4;
  int bx = 15 - (wgs & 15);
  int q0 = bx * 128;
  int bq = z >> 4, hh = z & 15;
  int t = threadIdx.x, lane = t & 63, wid = t >> 6;
  int lr = lane & 15, kgp = lane >> 4;
  const unsigned short* cb = c + (long)bq * Ss * (3 * Dd) + hh * DHh; // row s: +s*3072
  const unsigned short* kp = kp16 + (long)z * Pp * DHh;
  const unsigned short* vz = vTg + (long)z * DHh * NS;
  float* wz = wg + (long)z * Ss * NS;

  short8 qa[2][2];
#pragma unroll
  for (int i = 0; i < 2; i++)
#pragma unroll
    for (int kk = 0; kk < 2; kk++)
      qa[i][kk] = *(const short8*)(cb + (long)(q0 + wid * 32 + i * 16 + lr) * (3 * Dd) +
                                   kk * 32 + kgp * 8);

  const int nt = bx + 2;
  float l_run[2][4] = {};

// K tile staging: kt==0 from kp16 (past), else from c's K section
#define STAGE_K(kt_)                                                                   \
  do {                                                                                 \
    if ((kt_) == 0) {                                                                  \
      _Pragma("unroll") for (int it = 0; it < 4; it++) {                               \
        int idx = t + it * 256, row = idx >> 3, c8 = (idx & 7) * 8;                    \
        *(short8*)&KV[row * 72 + c8] = *(const short8*)(kp + (long)row * DHh + c8);    \
      }                                                                                \
    } else {                                                                           \
      _Pragma("unroll") for (int it = 0; it < 4; it++) {                               \
        int idx = t + it * 256, row = idx >> 3, c8 = (idx & 7) * 8;                    \
        *(short8*)&KV[row * 72 + c8] = *(const short8*)(                               \
            cb + (long)(((kt_)-1) * 128 + row) * (3 * Dd) + Dd + c8);                  \
      }                                                                                \
    }                                                                                  \
  } while (0)

  // ---- pass 1: denominators (fixed max M0=8) ----
  for (int kt = 0; kt < nt; kt++) {
    STAGE_K(kt);
    SYNC_LDS();
    floatx4 acc[2][8] = {};
    __builtin_amdgcn_s_setprio(1);
#pragma unroll
    for (int j = 0; j < 8; j++) {
      short8 b0 = *(const short8*)&KV[(j * 16 + lr) * 72 + kgp * 8];
      short8 b1 = *(const short8*)&KV[(j * 16 + lr) * 72 + 32 + kgp * 8];
#pragma unroll
      for (int i = 0; i < 2; i++) {
        acc[i][j] = __builtin_amdgcn_mfma_f32_16x16x32_bf16(qa[i][0], b0, acc[i][j], 0, 0, 0);
        acc[i][j] = __builtin_amdgcn_mfma_f32_16x16x32_bf16(qa[i][1], b1, acc[i][j], 0, 0, 0);
      }
    }
    __builtin_amdgcn_s_setprio(0);
#pragma unroll
    for (int i = 0; i < 2; i++) {
#pragma unroll
      for (int r = 0; r < 4; r++) {
        int row = q0 + wid * 32 + i * 16 + kgp * 4 + r;
        float su = 0.f;
#pragma unroll
        for (int j = 0; j < 8; j++) {
          int col = kt * 128 + j * 16 + lr;
          su += (col > row + Pp) ? 0.f : __expf(acc[i][j][r] * 0.125f - 8.0f);
        }
        su += __shfl_xor(su, 1);
        su += __shfl_xor(su, 2);
        su += __shfl_xor(su, 4);
        su += __shfl_xor(su, 8);
        l_run[i][r] += su;
      }
    }
    SYNC_LDS();
  }

  float cc[2][4];
#pragma unroll
  for (int i = 0; i < 2; i++)
#pragma unroll
    for (int r = 0; r < 4; r++) cc[i][r] = 8.0f + __logf(l_run[i][r]);

  // ---- pass 2: w + PV ----
  floatx4 oacc[2][4] = {};
  for (int kt = 0; kt < nt; kt++) {
    STAGE_K(kt);
    SYNC_LDS();
    floatx4 acc[2][8] = {};
    __builtin_amdgcn_s_setprio(1);
#pragma unroll
    for (int j = 0; j < 8; j++) {
      short8 b0 = *(const short8*)&KV[(j * 16 + lr) * 72 + kgp * 8];
      short8 b1 = *(const short8*)&KV[(j * 16 + lr) * 72 + 32 + kgp * 8];
#pragma unroll
      for (int i = 0; i < 2; i++) {
        acc[i][j] = __builtin_amdgcn_mfma_f32_16x16x32_bf16(qa[i][0], b0, acc[i][j], 0, 0, 0);
        acc[i][j] = __builtin_amdgcn_mfma_f32_16x16x32_bf16(qa[i][1], b1, acc[i][j], 0, 0, 0);
      }
    }
    __builtin_amdgcn_s_setprio(0);
#pragma unroll
    for (int i = 0; i < 2; i++) {
#pragma unroll
      for (int r = 0; r < 4; r++) {
        int row = q0 + wid * 32 + i * 16 + kgp * 4 + r;
#pragma unroll
        for (int j = 0; j < 8; j++) {
          int col = kt * 128 + j * 16 + lr;
          float p = (col > row + Pp) ? 0.f : __expf(acc[i][j][r] * 0.125f - cc[i][r]);
          Pl[(wid * 32 + i * 16 + kgp * 4 + r) * 136 + j * 16 + lr] = f2bf(p);
        }
      }
    }
    SYNC_LDS(); // K readers done + Pl visible
    // stage V^T + coalesced w stores from Pl
#pragma unroll
    for (int it = 0; it < 4; it++) {
      int idx = t + it * 256, row = idx >> 4, c8 = (idx & 15) * 8;
      *(short8*)&KV[row * 136 + c8] = *(const short8*)(vz + (long)row * NS + kt * 128 + c8);
    }
    {
      int prow = t >> 5, pcol = (t & 31) * 4;
#pragma unroll
      for (int it = 0; it < 16; it++) {
        int row = it * 8 + prow;
        float4 f;
        f.x = bf2f(Pl[row * 136 + pcol]);
        f.y = bf2f(Pl[row * 136 + pcol + 1]);
        f.z = bf2f(Pl[row * 136 + pcol + 2]);
        f.w = bf2f(Pl[row * 136 + pcol + 3]);
        *(float4*)&wz[(long)(q0 + row) * NS + kt * 128 + pcol] = f;
      }
    }
    SYNC_LDS(); // V^T staged
    __builtin_amdgcn_s_setprio(1);
#pragma unroll
    for (int kk = 0; kk < 4; kk++) {
      short8 pa[2];
#pragma unroll
      for (int i = 0; i < 2; i++)
        pa[i] = *(const short8*)&Pl[(wid * 32 + i * 16 + lr) * 136 + kk * 32 + kgp * 8];
#pragma unroll
      for (int jd = 0; jd < 4; jd++) {
        short8 bv = *(const short8*)&KV[(jd * 16 + lr) * 136 + kk * 32 + kgp * 8];
#pragma unroll
        for (int i = 0; i < 2; i++)
          oacc[i][jd] = __builtin_amdgcn_mfma_f32_16x16x32_bf16(pa[i], bv, oacc[i][jd], 0, 0, 0);
      }
    }
    __builtin_amdgcn_s_setprio(0);
    SYNC_LDS(); // PV readers done before next K staging
  }
#undef STAGE_K

  int zc0 = nt * 128;
  if (zc0 < NS) {
    for (int rr = 0; rr < 32; rr++) {
      int row = q0 + wid * 32 + rr;
      for (int cix = zc0 + (lane << 2); cix < NS; cix += 256) {
        float4 z4 = {0.f, 0.f, 0.f, 0.f};
        *(float4*)&wz[(long)row * NS + cix] = z4;
      }
    }
  }

#pragma unroll
  for (int i = 0; i < 2; i++)
#pragma unroll
    for (int jd = 0; jd < 4; jd++)
#pragma unroll
      for (int r = 0; r < 4; r++) {
        long row = (long)bq * Ss + q0 + wid * 32 + i * 16 + kgp * 4 + r;
        int col = hh * 64 + jd * 16 + lr;
        am[row * Dd + col] = f2bf(oacc[i][jd][r]);
      }
}

// --- bf16 MFMA GEMM: m97 staging + dbuf prefetch; tile size templated ---
enum { EPI_BF16_BIAS = 0, EPI_RES = 3, EPI_GELU = 4 };

template <int EPI, int BM, int BN, int NB>
__global__ __launch_bounds__(256) void gemm_k(const unsigned short* __restrict__ A16,
                                              const unsigned short* __restrict__ Bt,
                                              const float* __restrict__ bias,
                                              const float* __restrict__ res,
                                              void* __restrict__ outv,
                                              int M, int N, int K, int nwg) {
  constexpr int WTM = BM / 2, WTN = BN / 2;
  constexpr int FM = WTM / 16, FN = WTN / 16;
  constexpr int IA = BM / 64, IB = BN / 64; // gload_lds issues per wave (16 rows each)
  __shared__ unsigned short Alds[2][BM * 32];
  __shared__ unsigned short Blds[2][BN * 32];
  int cpx = nwg >> 3;
  int wgid = (blockIdx.x & 7) * cpx + (blockIdx.x >> 3);
  int mb = wgid / NB, nb = wgid % NB;
  int m0 = mb * BM, n0 = nb * BN;
  int t = threadIdx.x;
  int lane = t & 63, wid = t >> 6;
  int wm = wid >> 1, wn = wid & 1;
  floatx4 acc[FM][FN] = {};
  int lr = lane & 15, kg = lane >> 4;

  int srow = lane >> 2, skc = (lane & 3) * 8;
  const unsigned short* Ab = A16 + (long)(m0 + wid * (BM / 4) + srow) * K + skc;
  const unsigned short* Bp = Bt + (long)(n0 + wid * (BN / 4) + srow) * K + skc;
  long rstride = (long)16 * K;

#define STAGE(bb, k0)                                                         \
  do {                                                                        \
    _Pragma("unroll") for (int ii = 0; ii < IA; ii++)                         \
        gl_lds16(Ab + ii * rstride + (k0),                                    \
                 &Alds[bb][(wid * (BM / 4) + ii * 16) * 32]);                 \
    _Pragma("unroll") for (int ii = 0; ii < IB; ii++)                         \
        gl_lds16(Bp + ii * rstride + (k0),                                    \
                 &Blds[bb][(wid * (BN / 4) + ii * 16) * 32]);                 \
  } while (0)

  STAGE(0, 0);
  SYNC_VM();
  int cur = 0;
  int nt = K >> 5;
  for (int tt = 0; tt < nt; tt++) {
    if (tt + 1 < nt) STAGE(cur ^ 1, (tt + 1) * 32);
    short8 a[FM], b[FN];
#pragma unroll
    for (int i = 0; i < FM; i++)
      a[i] = *(const short8*)&Alds[cur][(wm * WTM + i * 16 + lr) * 32 + kg * 8];
#pragma unroll
    for (int j = 0; j < FN; j++)
      b[j] = *(const short8*)&Blds[cur][(wn * WTN + j * 16 + lr) * 32 + kg * 8];
    __builtin_amdgcn_s_setprio(1);
#pragma unroll
    for (int i = 0; i < FM; i++)
#pragma unroll
      for (int j = 0; j < FN; j++)
        acc[i][j] = __builtin_amdgcn_mfma_f32_16x16x32_bf16(a[i], b[j], acc[i][j], 0, 0, 0);
    __builtin_amdgcn_s_setprio(0);
    SYNC_VM();
    cur ^= 1;
  }
#undef STAGE

#pragma unroll
  for (int i = 0; i < FM; i++) {
#pragma unroll
    for (int j = 0; j < FN; j++) {
#pragma unroll
      for (int r = 0; r < 4; r++) {
        int mm = m0 + wm * WTM + i * 16 + kg * 4 + r;
        int nn = n0 + wn * WTN + j * 16 + lr;
        float v = acc[i][j][r];
        if constexpr (EPI == EPI_BF16_BIAS) {
          ((unsigned short*)outv)[(long)mm * N + nn] = f2bf(v + bias[nn]);
        } else if constexpr (EPI == EPI_RES) {
          ((float*)outv)[(long)mm * N + nn] = v + bias[nn] + res[(long)mm * N + nn];
        } else if constexpr (EPI == EPI_GELU) {
          float xv = v + bias[nn];
          float u = xv + 0.044715f * xv * xv * xv;
          float tv = 1.0f - 2.0f / (__expf(1.5957691216057308f * u) + 1.0f);
          ((unsigned short*)outv)[(long)mm * N + nn] = f2bf(0.5f * xv * (1.0f + tv));
        }
      }
    }
  }
}

extern "C" void kernel_launch(void* const* d_in, const int* in_sizes, int n_in,
                              void* d_out, int out_size, void* d_ws, size_t ws_size,
                              hipStream_t stream) {
  (void)in_sizes; (void)n_in; (void)out_size; (void)ws_size;
  const float* x = (const float*)d_in[0];
  const float* past = (const float*)d_in[1];
  const float* qkv_w = (const float*)d_in[2];
  const float* qkv_b = (const float*)d_in[3];
  const float* merge_w = (const float*)d_in[4];
  const float* merge_b = (const float*)d_in[5];
  const float* ln1_w = (const float*)d_in[6];
  const float* ln1_b = (const float*)d_in[7];
  const float* ln2_w = (const float*)d_in[8];
  const float* ln2_b = (const float*)d_in[9];
  const float* g1 = (const float*)d_in[10];
  const float* b1 = (const float*)d_in[11];
  const float* g2 = (const float*)d_in[12];
  const float* b2 = (const float*)d_in[13];

  char* ws = (char*)d_ws;
  unsigned short* qkv_wT = (unsigned short*)(ws + 0);         // 6.3 MB
  unsigned short* merge_wT = (unsigned short*)(ws + 6291456); // 2.1 MB
  unsigned short* ln1_wT = (unsigned short*)(ws + 8388608);   // 8.4 MB
  unsigned short* ln2_wT = (unsigned short*)(ws + 16777216);  // 8.4 MB
  unsigned short* h = (unsigned short*)(ws + 25165824);       // 8.4 MB (dead after QKV)
  unsigned short* am = (unsigned short*)(ws + 33554432);      // 8.4 MB (dead after merge)
  unsigned short* kp16 = (unsigned short*)(ws + 41943040);    // 0.5 MB
  unsigned short* vT = (unsigned short*)(ws + 50855936);      // 8.9 MB -> 59768832
  unsigned short* c = (unsigned short*)(ws + 59768832);       // 25.2 MB -> 84934656
  unsigned short* m1 = (unsigned short*)(ws + 25165824);      // 33.5 MB (after attn; h/am/kp16/vT dead)
  float* xa = (float*)(ws + 68157440);                        // 16.8 MB (c dead after attn)
  unsigned short* h2 = (unsigned short*)(ws + 84934656);      // 8.4 MB -> 93.3 MB total

  float* xm_out = (float*)d_out;
  float* present = ((float*)d_out) + (long)Bb * Ss * Dd;
  float* w_out = present + (long)Bb * 2 * Hh * Ss * DHh;

  wt_cvt_all_kernel<<<12288, 256, 0, stream>>>(qkv_w, merge_w, ln1_w, ln2_w,
                                               qkv_wT, merge_wT, ln1_wT, ln2_wT);

  ln_kernel<<<Bb * Ss, 256, 0, stream>>>(x, g1, b1, h);

  // c = LN(x) @ qkv_w + qkv_b
  gemm_k<EPI_BF16_BIAS, 128, 128, 24><<<32 * 24, 256, 0, stream>>>(
      h, qkv_wT, qkv_b, nullptr, c, 4096, 3072, 1024, 32 * 24);

  // present + past-K bf16 + vT past columns
  prep_kernel<<<18432, 256, 0, stream>>>(c, past, present, kp16, vT);

  // vT new columns from c's V section
  vtr_kernel<<<dim3(Ss / 64, Bb * Hh), 256, 0, stream>>>(c, vT);

  attn_kernel<<<512, 256, 0, stream>>>(c, kp16, vT, w_out, am);

  gemm_k<EPI_RES, 64, 128, 8><<<64 * 8, 256, 0, stream>>>(
      am, merge_wT, merge_b, x, xa, 4096, 1024, 1024, 64 * 8);

  ln_kernel<<<Bb * Ss, 256, 0, stream>>>(xa, g2, b2, h2);

  gemm_k<EPI_GELU, 128, 128, 32><<<32 * 32, 256, 0, stream>>>(
      h2, ln1_wT, ln1_b, nullptr, m1, 4096, 4096, 1024, 32 * 32);

  gemm_k<EPI_RES, 64, 128, 8><<<64 * 8, 256, 0, stream>>>(
      m1, ln2_wT, ln2_b, x, xm_out, 4096, 1024, 4096, 64 * 8);
}